// Round 1
// 2571.555 us; speedup vs baseline: 1.3285x; 1.3285x over previous
//
#include <hip/hip_runtime.h>
#include <math.h>

// Problem constants
#define B_   4096
#define D_   256
#define H_   266
#define T_   51
#define S_   50
#define HP   320        // padded row stride (fp32 activations), = 5*BK
#define EPSF 1e-5f

typedef __bf16 bf16_t;
typedef __bf16 bf16x8 __attribute__((ext_vector_type(8)));
typedef float  f32x4  __attribute__((ext_vector_type(4)));

// MFMA GEMM tile config: block 64x64, 4 waves (2x2), each wave 32x32 (2x2 MFMA frags)
// BK=64 k-step; K padded to 320 so the k-loop is always full-speed unguarded.
#define BM 64
#define BN 64
#define BK 64
#define LDST 72   // LDS row stride in bf16 (144 B: 16B-aligned, bank-skewed)

struct Job {
  const float* A; int lda; int Ka;                    // A: M x Ka fp32 (lda >= niter*BK)
  const float* g; const float* be;                    // BN-on-A params (bnA)
  const float* asum; const float* asq;
  int bnA;                                            // apply relu(BN(A)) while staging
  const bf16_t* Wt; int ldw;                          // Wt: N x ldw bf16, k-contig, zero-padded
  const float* bias;                                  // N
  const float* trow; const float* tg; int tidx;       // optional bias += tg[tidx]*trow[col]
  float* C; int ldc; int N; int relu;
  float* ssum; float* ssq;                            // optional column stats (atomic)
};

__device__ __forceinline__ void load16(const float* p, float* a) {
  const float4* q = (const float4*)p;
  float4 v0 = q[0], v1 = q[1], v2 = q[2], v3 = q[3];
  a[0]=v0.x; a[1]=v0.y; a[2]=v0.z;  a[3]=v0.w;
  a[4]=v1.x; a[5]=v1.y; a[6]=v1.z;  a[7]=v1.w;
  a[8]=v2.x; a[9]=v2.y; a[10]=v2.z; a[11]=v2.w;
  a[12]=v3.x; a[13]=v3.y; a[14]=v3.z; a[15]=v3.w;
}

__global__ __launch_bounds__(256) void mfma_gemm(Job j0, Job j1, float invB) {
  Job j = blockIdx.z ? j1 : j0;
  __shared__ bf16_t As[BM][LDST];
  __shared__ bf16_t Ws[BN][LDST];
  __shared__ float sc[HP], sh[HP];

  const int tid = threadIdx.x;
  const int r0 = blockIdx.y * BM;
  const int c0 = blockIdx.x * BN;

  // Precompute BN scale/shift for A columns (k-dim). Zero-fill padding so
  // garbage never reaches the MFMA (pad A elems become 0).
  if (j.bnA) {
    for (int k = tid; k < HP; k += 256) {
      if (k < j.Ka) {
        float mu  = j.asum[k] * invB;
        float var = j.asq[k] * invB - mu * mu;
        float s   = j.g[k] * rsqrtf(var + EPSF);
        sc[k] = s; sh[k] = j.be[k] - mu * s;
      } else { sc[k] = 0.f; sh[k] = 0.f; }
    }
  }

  const int wave = tid >> 6;
  const int lane = tid & 63;
  const int wr = (wave >> 1) * 32;
  const int wc = (wave & 1) * 32;
  const int l16 = lane & 15;
  const int lk8 = (lane >> 4) * 8;

  f32x4 acc[2][2] = {};

  const int arow = tid >> 2;          // 0..63
  const int kseg = (tid & 3) * 16;    // 0,16,32,48

  const int niter = (j.Ka + BK - 1) / BK;   // 4 (K=256) or 5 (K=266, lda=320)

  const float*  Abase = j.A + (size_t)(r0 + arow) * j.lda + kseg;
  const int     crow  = c0 + arow;
  const bf16_t* Wbase = j.Wt + (size_t)crow * j.ldw + kseg;
  const bool    wok   = crow < j.N;

  float a16[16];
  uint4 wv0 = make_uint4(0,0,0,0), wv1 = make_uint4(0,0,0,0);

  // prologue: load tile 0 into regs
  load16(Abase, a16);
  if (wok) {
    const uint4* q = (const uint4*)Wbase;
    wv0 = q[0]; wv1 = q[1];
  }

  for (int it = 0; it < niter; ++it) {
    const int kb = it * BK + kseg;

    __syncthreads();   // prior iter's LDS reads done (also covers sc/sh init)

    // ---- transform regs + write LDS ----
    bf16x8 p0, p1;
    if (j.bnA) {
      #pragma unroll
      for (int i = 0; i < 8; ++i)
        p0[i] = (bf16_t)fmaxf(fmaf(a16[i], sc[kb + i], sh[kb + i]), 0.f);
      #pragma unroll
      for (int i = 0; i < 8; ++i)
        p1[i] = (bf16_t)fmaxf(fmaf(a16[8 + i], sc[kb + 8 + i], sh[kb + 8 + i]), 0.f);
    } else {
      // branchless zero of k >= Ka (pad cols of raw-consumed buffers are garbage)
      #pragma unroll
      for (int i = 0; i < 8; ++i) {
        float t = (kb + i < j.Ka) ? a16[i] : 0.f;
        p0[i] = (bf16_t)t;
      }
      #pragma unroll
      for (int i = 0; i < 8; ++i) {
        float t = (kb + 8 + i < j.Ka) ? a16[8 + i] : 0.f;
        p1[i] = (bf16_t)t;
      }
    }
    *(bf16x8*)&As[arow][kseg]     = p0;
    *(bf16x8*)&As[arow][kseg + 8] = p1;
    *(uint4*)&Ws[arow][kseg]      = wv0;
    *(uint4*)&Ws[arow][kseg + 8]  = wv1;

    __syncthreads();

    // ---- prefetch next tile into regs (overlaps with MFMA below) ----
    if (it + 1 < niter) {
      load16(Abase + (size_t)(it + 1) * BK, a16);
      if (wok) {
        const uint4* q = (const uint4*)(Wbase + (size_t)(it + 1) * BK);
        wv0 = q[0]; wv1 = q[1];
      }
    }

    // ---- fragments + MFMA ----
    bf16x8 af[2][2], bfr[2][2];
    #pragma unroll
    for (int mi = 0; mi < 2; ++mi)
      #pragma unroll
      for (int kk = 0; kk < 2; ++kk)
        af[mi][kk] = *(const bf16x8*)&As[wr + mi*16 + l16][kk*32 + lk8];
    #pragma unroll
    for (int ni = 0; ni < 2; ++ni)
      #pragma unroll
      for (int kk = 0; kk < 2; ++kk)
        bfr[ni][kk] = *(const bf16x8*)&Ws[wc + ni*16 + l16][kk*32 + lk8];
    #pragma unroll
    for (int kk = 0; kk < 2; ++kk)
      #pragma unroll
      for (int mi = 0; mi < 2; ++mi)
        #pragma unroll
        for (int ni = 0; ni < 2; ++ni)
          acc[mi][ni] = __builtin_amdgcn_mfma_f32_16x16x32_bf16(af[mi][kk], bfr[ni][kk], acc[mi][ni], 0, 0, 0);
  }

  // ---- epilogue: bias (+t*trow), relu, store, column stats ----
  float tb = j.trow ? j.tg[j.tidx] : 0.f;
  #pragma unroll
  for (int ni = 0; ni < 2; ++ni) {
    int col = c0 + wc + ni*16 + l16;
    bool cok = col < j.N;
    float bias = cok ? j.bias[col] : 0.f;
    if (j.trow && cok) bias = fmaf(tb, j.trow[col], bias);
    float s = 0.f, q = 0.f;
    #pragma unroll
    for (int mi = 0; mi < 2; ++mi) {
      #pragma unroll
      for (int r = 0; r < 4; ++r) {
        float v = acc[mi][ni][r] + bias;       // col>=N: acc==0 (W zero-padded), bias 0
        if (j.relu) v = fmaxf(v, 0.f);
        int row = r0 + wr + mi*16 + ((lane >> 4) << 2) + r;
        if (cok) j.C[(size_t)row * j.ldc + col] = v;
        s += v; q += v * v;
      }
    }
    if (j.ssum) {
      s += __shfl_xor(s, 16); q += __shfl_xor(q, 16);
      s += __shfl_xor(s, 32); q += __shfl_xor(q, 32);
      if (lane < 16) {
        int col2 = c0 + wc + ni*16 + lane;
        if (col2 < j.N) { atomicAdd(&j.ssum[col2], s); atomicAdd(&j.ssq[col2], q); }
      }
    }
  }
}

// transpose + cast: out[s][n][k] = in[s][k][n] (k<K), zero-pad to Kp
__global__ __launch_bounds__(256) void wconv(const float* __restrict__ in, bf16_t* __restrict__ out,
                                             int K, int N, int Kp, int total) {
  for (int idx = blockIdx.x * 256 + threadIdx.x; idx < total; idx += gridDim.x * 256) {
    int k = idx % Kp; int rest = idx / Kp; int n = rest % N; int s = rest / N;
    float v = (k < K) ? in[((size_t)s * K + k) * N + n] : 0.f;
    out[idx] = (bf16_t)v;
  }
}

// y[r] = sum_k relu(BN(A[r,k])) * w[k] + b ; scalar stats via atomics
__global__ __launch_bounds__(256) void matvec_bn(const float* __restrict__ A, int lda,
                                                 const float* __restrict__ g, const float* __restrict__ be,
                                                 const float* __restrict__ asum, const float* __restrict__ asq,
                                                 const float* __restrict__ w, const float* __restrict__ bptr,
                                                 float* __restrict__ y, float* ssum, float* ssq,
                                                 int K, float invB) {
  int r = blockIdx.x;
  float acc = 0.f;
  for (int k = threadIdx.x; k < K; k += 256) {
    float mu  = asum[k] * invB;
    float var = asq[k] * invB - mu * mu;
    float s   = g[k] * rsqrtf(var + EPSF);
    float val = fmaxf(fmaf(A[(size_t)r * lda + k], s, be[k] - mu * s), 0.f);
    acc += val * w[k];
  }
  __shared__ float sred[256];
  sred[threadIdx.x] = acc; __syncthreads();
  for (int st = 128; st > 0; st >>= 1) {
    if (threadIdx.x < st) sred[threadIdx.x] += sred[threadIdx.x + st];
    __syncthreads();
  }
  if (threadIdx.x == 0) {
    float v = sred[0] + bptr[0];
    y[r] = v;
    atomicAdd(ssum, v); atomicAdd(ssq, v * v);
  }
}

__global__ __launch_bounds__(256) void v0_fin(const float* __restrict__ y, float* v,
                                              const float* g, const float* be,
                                              const float* ssum, const float* ssq,
                                              int M, float invM) {
  int r = blockIdx.x * blockDim.x + threadIdx.x;
  if (r < M) {
    float mu  = ssum[0] * invM;
    float var = ssq[0] * invM - mu * mu;
    float t = g[0] * (y[r] - mu) * rsqrtf(var + EPSF) + be[0];
    v[r] = fmaxf(t, 0.f);
  }
}

// wave-per-row update: 4 rows per block, pure shuffle reduction
__global__ __launch_bounds__(256) void update_step(const float* __restrict__ xc,
                                                   float* __restrict__ xn,
                                                   const float* __restrict__ alpha,
                                                   const float* __restrict__ grad,
                                                   const float* __restrict__ xi_i,
                                                   const float* __restrict__ law_i,
                                                   const float* __restrict__ tg, int i,
                                                   float* __restrict__ v) {
  const int lane = threadIdx.x & 63;
  const int wv   = threadIdx.x >> 6;
  const int r    = blockIdx.x * 4 + wv;
  const float hi = tg[i + 1] - tg[i];
  const float sq = sqrtf(hi);
  const size_t off = (size_t)r * D_ + lane * 4;
  float4 x4 = *(const float4*)(xc + off);
  float4 a4 = *(const float4*)(alpha + off);
  float4 g4 = *(const float4*)(grad + off);
  float4 z4 = *(const float4*)(xi_i + off);
  float4 l4 = *(const float4*)(law_i + lane * 4);
  float xv[4] = {x4.x, x4.y, x4.z, x4.w};
  float av[4] = {a4.x, a4.y, a4.z, a4.w};
  float gv[4] = {g4.x, g4.y, g4.z, g4.w};
  float zv[4] = {z4.x, z4.y, z4.z, z4.w};
  float lv[4] = {l4.x, l4.y, l4.z, l4.w};
  float sf = 0.f, si = 0.f;
  float ov[4];
  #pragma unroll
  for (int e = 0; e < 4; ++e) {
    float df = xv[e] - lv[e];
    sf += df * df + av[e] * av[e];
    si += gv[e] * zv[e];
    ov[e] = xv[e] + av[e] * hi + sq * zv[e];
  }
  #pragma unroll
  for (int d = 1; d < 64; d <<= 1) {
    sf += __shfl_xor(sf, d);
    si += __shfl_xor(si, d);
  }
  if (lane == 0) v[r] = v[r] - 0.5f * sf * hi + sq * si;
  float4 o; o.x = ov[0]; o.y = ov[1]; o.z = ov[2]; o.w = ov[3];
  *(float4*)(xn + off) = o;
}

extern "C" void kernel_launch(void* const* d_in, const int* in_sizes, int n_in,
                              void* d_out, int out_size, void* d_ws, size_t ws_size,
                              hipStream_t stream) {
  const float* x    = (const float*)d_in[0];
  const float* W1   = (const float*)d_in[1];
  const float* b1   = (const float*)d_in[2];
  const float* g1   = (const float*)d_in[3];
  const float* be1  = (const float*)d_in[4];
  const float* W2   = (const float*)d_in[5];
  const float* b2   = (const float*)d_in[6];
  const float* g2   = (const float*)d_in[7];
  const float* be2  = (const float*)d_in[8];
  const float* W3   = (const float*)d_in[9];
  const float* b3   = (const float*)d_in[10];
  const float* vW1  = (const float*)d_in[11];
  const float* vb1  = (const float*)d_in[12];
  const float* vg1  = (const float*)d_in[13];
  const float* vbe1 = (const float*)d_in[14];
  const float* vW2  = (const float*)d_in[15];
  const float* vb2  = (const float*)d_in[16];
  const float* vg2  = (const float*)d_in[17];
  const float* vbe2 = (const float*)d_in[18];
  const float* vW3  = (const float*)d_in[19];
  const float* vb3  = (const float*)d_in[20];
  const float* vg3  = (const float*)d_in[21];
  const float* vbe3 = (const float*)d_in[22];
  const float* aW1  = (const float*)d_in[23];
  const float* ab1  = (const float*)d_in[24];
  const float* aW2  = (const float*)d_in[25];
  const float* ab2  = (const float*)d_in[26];
  const float* law  = (const float*)d_in[27];
  const float* tg   = (const float*)d_in[28];
  const float* xi   = (const float*)d_in[29];

  float* out    = (float*)d_out;
  float* v_out  = out;
  float* xf_out = out + B_;
  float* path   = out + B_ + (size_t)B_ * D_;

  float* ws   = (float*)d_ws;
  float* h1   = ws;
  float* h2   = h1 + (size_t)B_ * HP;
  float* ah   = h2 + (size_t)B_ * HP;
  float* grad = ah + (size_t)B_ * HP;
  float* alp  = grad + (size_t)B_ * D_;
  float* yraw = alp + (size_t)B_ * D_;
  float* stats = yraw + B_;
  const int NSLOT = 2 * S_ + 3;

  bf16_t* wbuf = (bf16_t*)(stats + (size_t)NSLOT * 2 * HP);
  bf16_t* W1t  = wbuf;                                   // [50][266][256]
  bf16_t* W2t  = W1t + (size_t)S_ * H_ * 256;            // [50][266][320]
  bf16_t* W3t  = W2t + (size_t)S_ * H_ * 320;            // [50][256][320]
  bf16_t* aW1t = W3t + (size_t)S_ * 256 * 320;           // [266][256]
  bf16_t* aW2t = aW1t + (size_t)H_ * 256;                // [256][320]
  bf16_t* vW1t = aW2t + (size_t)256 * 320;               // [266][256]
  bf16_t* vW2t = vW1t + (size_t)H_ * 256;                // [266][320]

  hipMemsetAsync(stats, 0, (size_t)NSLOT * 2 * HP * sizeof(float), stream);
  hipMemcpyAsync(path, x, (size_t)B_ * D_ * sizeof(float), hipMemcpyDeviceToDevice, stream);

  auto ssum = [&](int s) { return stats + (size_t)s * 2 * HP; };
  auto ssq  = [&](int s) { return stats + (size_t)s * 2 * HP + HP; };

  dim3 blk(256);
  const float invB = 1.0f / (float)B_;
  const int MT   = B_ / BM;             // 64 row tiles
  const int NT_H = (H_ + BN - 1) / BN;  // 5 col tiles (266 -> 320)
  const int NT_D = D_ / BN;             // 4 col tiles

  // ---- one-time (per launch) weight transpose+cast ----
  wconv<<<dim3(1024), blk, 0, stream>>>(W1,        W1t,  256, H_,  256, S_ * H_ * 256);
  wconv<<<dim3(1024), blk, 0, stream>>>(W2,        W2t,  H_,  H_,  320, S_ * H_ * 320);
  wconv<<<dim3(1024), blk, 0, stream>>>(W3,        W3t,  H_,  256, 320, S_ * 256 * 320);
  wconv<<<dim3(256),  blk, 0, stream>>>(aW1 + H_,  aW1t, 256, H_,  256, H_ * 256);
  wconv<<<dim3(256),  blk, 0, stream>>>(aW2,       aW2t, H_,  256, 320, 256 * 320);
  wconv<<<dim3(256),  blk, 0, stream>>>(vW1,       vW1t, 256, H_,  256, H_ * 256);
  wconv<<<dim3(256),  blk, 0, stream>>>(vW2,       vW2t, H_,  H_,  320, H_ * 320);

  // ---- v0 = 3-layer BN-MLP on x ----
  {
    Job jv1 = {x, D_, D_, nullptr, nullptr, nullptr, nullptr, 0,
               vW1t, 256, vb1, nullptr, nullptr, 0,
               h1, HP, H_, 0, ssum(100), ssq(100)};
    mfma_gemm<<<dim3(NT_H, MT, 1), blk, 0, stream>>>(jv1, jv1, invB);
    Job jv2 = {h1, HP, H_, vg1, vbe1, ssum(100), ssq(100), 1,
               vW2t, 320, vb2, nullptr, nullptr, 0,
               h2, HP, H_, 0, ssum(101), ssq(101)};
    mfma_gemm<<<dim3(NT_H, MT, 1), blk, 0, stream>>>(jv2, jv2, invB);
    matvec_bn<<<dim3(B_), blk, 0, stream>>>(h2, HP, vg2, vbe2, ssum(101), ssq(101),
                                            vW3, vb3, yraw, ssum(102), ssq(102), H_, invB);
    v0_fin<<<dim3(16), blk, 0, stream>>>(yraw, v_out, vg3, vbe3, ssum(102), ssq(102), B_, invB);
  }

  // ---- scan ----
  for (int i = 0; i < S_; ++i) {
    const float* xc = path + (size_t)i * B_ * D_;
    float* xn       = path + (size_t)(i + 1) * B_ * D_;

    Job ja = {xc, D_, D_, nullptr, nullptr, nullptr, nullptr, 0,
              W1t + (size_t)i * H_ * 256, 256, b1 + (size_t)i * H_, nullptr, nullptr, 0,
              h1, HP, H_, 0, ssum(2 * i), ssq(2 * i)};
    Job jb = {xc, D_, D_, nullptr, nullptr, nullptr, nullptr, 0,
              aW1t, 256, ab1, aW1, tg, i,
              ah, HP, H_, 1, nullptr, nullptr};
    mfma_gemm<<<dim3(NT_H, MT, 2), blk, 0, stream>>>(ja, jb, invB);

    Job jc = {h1, HP, H_, g1 + (size_t)i * H_, be1 + (size_t)i * H_, ssum(2 * i), ssq(2 * i), 1,
              W2t + (size_t)i * H_ * 320, 320, b2 + (size_t)i * H_, nullptr, nullptr, 0,
              h2, HP, H_, 0, ssum(2 * i + 1), ssq(2 * i + 1)};
    mfma_gemm<<<dim3(NT_H, MT, 1), blk, 0, stream>>>(jc, jc, invB);

    Job jd = {h2, HP, H_, g2 + (size_t)i * H_, be2 + (size_t)i * H_, ssum(2 * i + 1), ssq(2 * i + 1), 1,
              W3t + (size_t)i * 256 * 320, 320, b3 + (size_t)i * D_, nullptr, nullptr, 0,
              grad, D_, D_, 0, nullptr, nullptr};
    Job je = {ah, HP, H_, nullptr, nullptr, nullptr, nullptr, 0,
              aW2t, 320, ab2, nullptr, nullptr, 0,
              alp, D_, D_, 0, nullptr, nullptr};
    mfma_gemm<<<dim3(NT_D, MT, 2), blk, 0, stream>>>(jd, je, invB);

    update_step<<<dim3(B_ / 4), blk, 0, stream>>>(xc, xn, alp, grad,
                                                  xi + (size_t)i * B_ * D_,
                                                  law + (size_t)i * D_, tg, i, v_out);
  }

  hipMemcpyAsync(xf_out, path + (size_t)S_ * B_ * D_,
                 (size_t)B_ * D_ * sizeof(float), hipMemcpyDeviceToDevice, stream);
}